// Round 2
// baseline (1414.381 us; speedup 1.0000x reference)
//
#include <hip/hip_runtime.h>
#include <math.h>

#define D_MODEL 1024
#define MEM_HEADS 4
#define KNN 32
#define KEY_DIM 288
#define VALUE_DIM 512
#define Q_RANK 512
#define NUM_BUCKETS 18
#define BUCKET_DIM 16
#define NTOK 2048                      // BATCH * SEQ
#define ROWS (NTOK * MEM_HEADS)        // 8192
#define QDIM (MEM_HEADS * KEY_DIM)     // 1152

typedef __attribute__((ext_vector_type(8))) short bfrag;   // 8 bf16 halves (4 VGPRs)
typedef __attribute__((ext_vector_type(4))) float f32x4;   // MFMA C/D frag

__device__ __forceinline__ unsigned short f2bf(float x) {  // RNE fp32->bf16
    unsigned int u = __builtin_bit_cast(unsigned int, x);
    u += 0x7FFFu + ((u >> 16) & 1u);
    return (unsigned short)(u >> 16);
}
__device__ __forceinline__ float bf2f(unsigned short h) {
    unsigned int u = ((unsigned int)h) << 16;
    return __builtin_bit_cast(float, u);
}

// ---------------------------------------------------------------------------
// Split-bf16 MFMA GEMM: C[M,N] = A[M,K] @ B[N,K]^T (+bias). fp32 in/out.
// REVERTED to the round-0 form (868 us verified). Round-1's pre-split-plane
// variant (pure load->LDS inner loop, 6 global streams) regressed the GEMM
// path ~1.6x: these small GEMMs are latency/barrier-bound at 1 block/CU, so
// the in-loop split conversion is hidden, and the extra prep kernel + extra
// bf16x3 bytes + 6-stream loads only added cost. Do not re-attempt without
// per-kernel timing evidence.
// MODE=3 (bf16x6): fp32-equivalent, REQUIRED for the q path (trellis
//   compares penalties at ~1e-5 separation). MODE=2 (bf16x3): OK for GEMM3.
// 64x64 tile, BK=32, 256 threads; 4 waves 2x2, each wave 2x2 16x16x32 tiles.
// LDS row stride 40 halves; frag layouts per m89/m91.
// ---------------------------------------------------------------------------
#define LSTR 40
template<int MODE>
__global__ __launch_bounds__(256) void gemm_nt_split(
    const float* __restrict__ A, const float* __restrict__ B,
    const float* __restrict__ bias, float* __restrict__ C,
    int M, int N, int K)
{
    __shared__ __align__(16) unsigned short As[MODE][64][LSTR];
    __shared__ __align__(16) unsigned short Bs[MODE][64][LSTR];

    const int tid  = threadIdx.x;
    const int bm   = blockIdx.y * 64;
    const int bn   = blockIdx.x * 64;
    const int wave = tid >> 6;
    const int lane = tid & 63;
    const int wr   = wave & 1;          // wave m-half (32 rows)
    const int wc   = wave >> 1;         // wave n-half (32 cols)
    const int l15  = lane & 15;
    const int quad = lane >> 4;

    const int sr = tid >> 2;            // staging row 0..63
    const int sg = tid & 3;             // staging 8-float segment

    f32x4 acc[2][2];
#pragma unroll
    for (int i = 0; i < 2; ++i)
#pragma unroll
        for (int j = 0; j < 2; ++j) acc[i][j] = (f32x4){0.f, 0.f, 0.f, 0.f};

    const float* Ap = A + (size_t)(bm + sr) * K + sg * 8;
    const float* Bp = B + (size_t)(bn + sr) * K + sg * 8;

    for (int k0 = 0; k0 < K; k0 += 32) {
        const float4 a0 = *(const float4*)(Ap + k0);
        const float4 a1 = *(const float4*)(Ap + k0 + 4);
        const float4 b0 = *(const float4*)(Bp + k0);
        const float4 b1 = *(const float4*)(Bp + k0 + 4);

        __syncthreads();   // prior chunk's frag reads done
        {
            const float va[8] = {a0.x,a0.y,a0.z,a0.w, a1.x,a1.y,a1.z,a1.w};
            const float vb[8] = {b0.x,b0.y,b0.z,b0.w, b1.x,b1.y,b1.z,b1.w};
            bfrag ha[MODE], hb[MODE];
#pragma unroll
            for (int i = 0; i < 8; ++i) {
                float xa = va[i], xb = vb[i];
#pragma unroll
                for (int s = 0; s < MODE; ++s) {
                    const unsigned short sa = f2bf(xa), sb = f2bf(xb);
                    ha[s][i] = (short)sa; hb[s][i] = (short)sb;
                    xa -= bf2f(sa);       xb -= bf2f(sb);
                }
            }
#pragma unroll
            for (int s = 0; s < MODE; ++s) {
                *(bfrag*)&As[s][sr][sg * 8] = ha[s];
                *(bfrag*)&Bs[s][sr][sg * 8] = hb[s];
            }
        }
        __syncthreads();   // tiles visible

        bfrag af[MODE][2], bf[MODE][2];
#pragma unroll
        for (int t = 0; t < 2; ++t) {
            const int mr = wr * 32 + t * 16 + l15;
            const int nr = wc * 32 + t * 16 + l15;
#pragma unroll
            for (int s = 0; s < MODE; ++s) {
                af[s][t] = *(const bfrag*)&As[s][mr][quad * 8];
                bf[s][t] = *(const bfrag*)&Bs[s][nr][quad * 8];
            }
        }
#pragma unroll
        for (int mt = 0; mt < 2; ++mt)
#pragma unroll
            for (int nt = 0; nt < 2; ++nt) {
                f32x4 c = acc[mt][nt];
                c = __builtin_amdgcn_mfma_f32_16x16x32_bf16(af[0][mt], bf[0][nt], c, 0, 0, 0);
                c = __builtin_amdgcn_mfma_f32_16x16x32_bf16(af[0][mt], bf[1][nt], c, 0, 0, 0);
                c = __builtin_amdgcn_mfma_f32_16x16x32_bf16(af[1][mt], bf[0][nt], c, 0, 0, 0);
                if (MODE == 3) {
                    c = __builtin_amdgcn_mfma_f32_16x16x32_bf16(af[1][mt], bf[1][nt], c, 0, 0, 0);
                    c = __builtin_amdgcn_mfma_f32_16x16x32_bf16(af[0][mt], bf[2][nt], c, 0, 0, 0);
                    c = __builtin_amdgcn_mfma_f32_16x16x32_bf16(af[2][mt], bf[0][nt], c, 0, 0, 0);
                }
                acc[mt][nt] = c;
            }
    }

    // epilogue: C/D frag (col=l15, row=quad*4+g) -> row-major C (+bias)
#pragma unroll
    for (int nt = 0; nt < 2; ++nt) {
        const int col = bn + wc * 32 + nt * 16 + l15;
        const float bv = bias ? bias[col] : 0.f;
#pragma unroll
        for (int mt = 0; mt < 2; ++mt) {
            const int rowb = bm + wr * 32 + mt * 16 + quad * 4;
#pragma unroll
            for (int g = 0; g < 4; ++g)
                C[(size_t)(rowb + g) * N + col] = acc[mt][nt][g] + bv;
        }
    }
}

// ---------------------------------------------------------------------------
// Trellis beam search — NEW merge engine, SAME math.
// Old version: LDS ping-pong two-pointer merge. The i/j pointers depend on
// the previous compare, so each of the 478 outputs is a serial chain
// (addr -> ds_read ~120cy -> compare) with 1 wave/SIMD and nothing to hide
// it: ~32 us. New version: beam lives entirely in registers (all indices
// compile-time, fully unrolled -> no scratch) and each step merges sorted A
// with B = A + d via a bitonic half-cleaner + 5-stage bitonic merge:
//   L[i] = min(A[i], B[31-i])  -> the 32 smallest, as a bitonic sequence
//   bitonic merge (k = 16,8,4,2,1) -> sorted ascending
// 112 compare-exchanges * ~5 VALU * 18 steps ~= 10K VALU, zero LDS on the
// critical path -> ~9 us predicted.
// Numerics: penalty values use the identical single add (pen + d) as the
// two-pointer version; for distinct values sorted-asc output is unique, so
// scores/indices match jax.lax.top_k bit-for-bit. CE tie direction is <=
// (A-side preferred) to mirror the reference's stable tie-break; exact fp
// ties are the only divergence risk (measure-zero for this input).
// Padding slots = 3e38 sentinel (same semantics as old code's 3.4e38):
// sentinel+d == sentinel, always sorts last, eliminated once 32 finite
// candidates exist (step 4).
// ---------------------------------------------------------------------------
__global__ __launch_bounds__(64) void trellis_kernel(
    const float* __restrict__ q, const float* __restrict__ keys,
    float* __restrict__ sc_out, int* __restrict__ idx_out)
{
    __shared__ float s_keys[MEM_HEADS * NUM_BUCKETS * 2 * BUCKET_DIM]; // 2304

    const int tid = threadIdx.x;
    for (int i = tid; i < MEM_HEADS * NUM_BUCKETS * 2 * BUCKET_DIM; i += 64)
        s_keys[i] = keys[i];
    __syncthreads();

    const int r = blockIdx.x * 64 + tid;
    const int h = r & 3;
    const float* qr = q + (size_t)r * KEY_DIM;

    float dlt[NUM_BUCKETS];
    int code = 0;
#pragma unroll
    for (int m = 0; m < NUM_BUCKETS; ++m) {
        const float* km = s_keys + h * (NUM_BUCKETS * 32) + m * 32;
        const float4 q0 = *(const float4*)(qr + m * BUCKET_DIM);
        const float4 q1 = *(const float4*)(qr + m * BUCKET_DIM + 4);
        const float4 q2 = *(const float4*)(qr + m * BUCKET_DIM + 8);
        const float4 q3 = *(const float4*)(qr + m * BUCKET_DIM + 12);
        const float qv[16] = {q0.x,q0.y,q0.z,q0.w, q1.x,q1.y,q1.z,q1.w,
                              q2.x,q2.y,q2.z,q2.w, q3.x,q3.y,q3.z,q3.w};
        float s0 = 0.f, s1 = 0.f;
#pragma unroll
        for (int d = 0; d < BUCKET_DIM; ++d) {
            s0 += qv[d] * km[d];
            s1 += qv[d] * km[16 + d];
        }
        dlt[m] = fabsf(s0 - s1);
        if (s1 > s0) code |= (1 << m);
    }

    // beam in registers, sorted ascending by penalty at every step
    float pen[KNN];
    int   msk[KNN];
    pen[0] = 0.f; msk[0] = 0;
#pragma unroll
    for (int i = 1; i < KNN; ++i) { pen[i] = 3.0e38f; msk[i] = 0; }

#pragma unroll
    for (int t = 0; t < NUM_BUCKETS; ++t) {
        const float d   = dlt[t];
        const int   bit = 1 << t;
        float np[KNN]; int nm[KNN];
        // half-cleaner: 32 smallest of A (asc) ∪ A+d (asc), bitonic order
#pragma unroll
        for (int i = 0; i < KNN; ++i) {
            const float pb = pen[KNN - 1 - i] + d;
            const int   mb = msk[KNN - 1 - i] ^ bit;
            const bool  ta = pen[i] <= pb;          // tie -> A side (top_k)
            np[i] = ta ? pen[i] : pb;
            nm[i] = ta ? msk[i] : mb;
        }
        // bitonic merge: sorts a bitonic sequence ascending
#pragma unroll
        for (int k = 16; k >= 1; k >>= 1) {
#pragma unroll
            for (int i = 0; i < KNN; ++i) {
                if ((i & k) == 0) {                 // compile-time predicate
                    const int jj = i | k;
                    const float a = np[i], b = np[jj];
                    const bool  ta = a <= b;
                    const float lo = ta ? a : b;
                    const float hi = ta ? b : a;
                    const int   ml = ta ? nm[i] : nm[jj];
                    const int   mh = ta ? nm[jj] : nm[i];
                    np[i] = lo; np[jj] = hi;
                    nm[i] = ml; nm[jj] = mh;
                }
            }
        }
#pragma unroll
        for (int i = 0; i < KNN; ++i) { pen[i] = np[i]; msk[i] = nm[i]; }
    }

    // softmax: penalty 0 always survives => softmax(best - pen) == exp(-pen)/Z
    float e[KNN];
    float Z = 0.f;
#pragma unroll
    for (int i = 0; i < KNN; ++i) {
        e[i] = expf(-pen[i]);
        Z += e[i];
    }
    const float inv = 1.0f / Z;
#pragma unroll
    for (int i = 0; i < KNN; ++i) {
        sc_out[(size_t)r * KNN + i]  = e[i] * inv;
        idx_out[(size_t)r * KNN + i] = code ^ msk[i];
    }
}

// ---------------------------------------------------------------------------
// Gather + embedding-bag: y[n,:] = sum_k score[n,k] * values[idx[n,k],:]
// One block (128 threads) per token; unroll 8 keeps ~8 float4 loads in
// flight per lane. At its roofline: 512 MB of mandatory random 2KB-row
// reads, L3 flushed by the harness's 2 GiB workspace fill each iteration
// -> ~85-100 us cold-HBM floor. Left byte-identical to the 868-us version.
// ---------------------------------------------------------------------------
__global__ __launch_bounds__(128) void gather_kernel(
    const float* __restrict__ sc, const int* __restrict__ idx,
    const float* __restrict__ values, float* __restrict__ y)
{
    __shared__ float s_s[MEM_HEADS * KNN];
    __shared__ int   s_i[MEM_HEADS * KNN];
    const int n = blockIdx.x;
    const int t = threadIdx.x;          // 0..127
    s_s[t] = sc[(size_t)n * 128 + t];
    s_i[t] = idx[(size_t)n * 128 + t];
    __syncthreads();

    float4 acc = {0.f, 0.f, 0.f, 0.f};
#pragma unroll 8
    for (int k = 0; k < 128; ++k) {
        const float4 v = *(const float4*)(values + (size_t)s_i[k] * VALUE_DIM + t * 4);
        const float w = s_s[k];
        acc.x += w * v.x; acc.y += w * v.y;
        acc.z += w * v.z; acc.w += w * v.w;
    }
    *(float4*)(y + (size_t)n * VALUE_DIM + t * 4) = acc;
}

// ---------------------------------------------------------------------------
extern "C" void kernel_launch(void* const* d_in, const int* in_sizes, int n_in,
                              void* d_out, int out_size, void* d_ws, size_t ws_size,
                              hipStream_t stream)
{
    (void)in_sizes; (void)n_in; (void)out_size; (void)ws_size;
    const float* x      = (const float*)d_in[0];
    const float* keys   = (const float*)d_in[1];
    const float* qd_w   = (const float*)d_in[2];
    const float* qd_b   = (const float*)d_in[3];
    const float* qu_w   = (const float*)d_in[4];
    const float* values = (const float*)d_in[5];
    const float* vp_w   = (const float*)d_in[6];
    float* out = (float*)d_out;

    float* q_mid = (float*)d_ws;                       // 2048*512
    float* q     = q_mid + (size_t)NTOK * Q_RANK;      // 2048*1152
    float* sc    = q + (size_t)NTOK * QDIM;            // 8192*32
    int*   idx   = (int*)(sc + (size_t)ROWS * KNN);    // 8192*32
    float* y     = (float*)(idx + (size_t)ROWS * KNN); // 2048*512

    // q_mid = x @ qd_w^T + qd_b    [2048,1024]@[512,1024]^T  (fp32-equiv)
    gemm_nt_split<3><<<dim3(Q_RANK / 64, NTOK / 64), 256, 0, stream>>>(
        x, qd_w, qd_b, q_mid, NTOK, Q_RANK, D_MODEL);
    // q = q_mid @ qu_w^T           [2048,512]@[1152,512]^T   (fp32-equiv)
    gemm_nt_split<3><<<dim3(QDIM / 64, NTOK / 64), 256, 0, stream>>>(
        q_mid, qu_w, nullptr, q, NTOK, QDIM, Q_RANK);
    // beam search -> softmaxed scores + indices (in-register bitonic merge)
    trellis_kernel<<<ROWS / 64, 64, 0, stream>>>(q, keys, sc, idx);
    // weighted gather -> y [2048, 512]
    gather_kernel<<<NTOK, 128, 0, stream>>>(sc, idx, values, y);
    // out = y @ vp_w^T             [2048,512]@[1024,512]^T   (bf16x3 ok)
    gemm_nt_split<2><<<dim3(D_MODEL / 64, NTOK / 64), 256, 0, stream>>>(
        y, vp_w, nullptr, out, NTOK, D_MODEL, VALUE_DIM);
}

// Round 3
// 784.928 us; speedup vs baseline: 1.8019x; 1.8019x over previous
//
#include <hip/hip_runtime.h>
#include <math.h>

#define D_MODEL 1024
#define MEM_HEADS 4
#define KNN 32
#define KEY_DIM 288
#define VALUE_DIM 512
#define Q_RANK 512
#define NUM_BUCKETS 18
#define BUCKET_DIM 16
#define NTOK 2048                      // BATCH * SEQ
#define ROWS (NTOK * MEM_HEADS)        // 8192
#define QDIM (MEM_HEADS * KEY_DIM)     // 1152

typedef __attribute__((ext_vector_type(8))) short bfrag;   // 8 bf16 halves (4 VGPRs)
typedef __attribute__((ext_vector_type(4))) float f32x4;   // MFMA C/D frag

__device__ __forceinline__ unsigned short f2bf(float x) {  // RNE fp32->bf16
    unsigned int u = __builtin_bit_cast(unsigned int, x);
    u += 0x7FFFu + ((u >> 16) & 1u);
    return (unsigned short)(u >> 16);
}
__device__ __forceinline__ float bf2f(unsigned short h) {
    unsigned int u = ((unsigned int)h) << 16;
    return __builtin_bit_cast(float, u);
}

// ---------------------------------------------------------------------------
// Split-bf16 MFMA GEMM: C[M,N] = A[M,K] @ B[N,K]^T (+bias). fp32 in/out.
// Round-0 form (868 us verified) — do not touch. Round-1's pre-split-plane
// variant regressed ~1.6x (latency/barrier-bound at 1 block/CU; in-loop
// split conversion is hidden, extra streams/prep only added cost).
// MODE=3 (bf16x6): fp32-equivalent, REQUIRED for the q path (trellis
//   compares penalties at ~1e-5 separation). MODE=2 (bf16x3): OK for GEMM3.
// 64x64 tile, BK=32, 256 threads; 4 waves 2x2, each wave 2x2 16x16x32 tiles.
// LDS row stride 40 halves; frag layouts per m89/m91.
// ---------------------------------------------------------------------------
#define LSTR 40
template<int MODE>
__global__ __launch_bounds__(256) void gemm_nt_split(
    const float* __restrict__ A, const float* __restrict__ B,
    const float* __restrict__ bias, float* __restrict__ C,
    int M, int N, int K)
{
    __shared__ __align__(16) unsigned short As[MODE][64][LSTR];
    __shared__ __align__(16) unsigned short Bs[MODE][64][LSTR];

    const int tid  = threadIdx.x;
    const int bm   = blockIdx.y * 64;
    const int bn   = blockIdx.x * 64;
    const int wave = tid >> 6;
    const int lane = tid & 63;
    const int wr   = wave & 1;          // wave m-half (32 rows)
    const int wc   = wave >> 1;         // wave n-half (32 cols)
    const int l15  = lane & 15;
    const int quad = lane >> 4;

    const int sr = tid >> 2;            // staging row 0..63
    const int sg = tid & 3;             // staging 8-float segment

    f32x4 acc[2][2];
#pragma unroll
    for (int i = 0; i < 2; ++i)
#pragma unroll
        for (int j = 0; j < 2; ++j) acc[i][j] = (f32x4){0.f, 0.f, 0.f, 0.f};

    const float* Ap = A + (size_t)(bm + sr) * K + sg * 8;
    const float* Bp = B + (size_t)(bn + sr) * K + sg * 8;

    for (int k0 = 0; k0 < K; k0 += 32) {
        const float4 a0 = *(const float4*)(Ap + k0);
        const float4 a1 = *(const float4*)(Ap + k0 + 4);
        const float4 b0 = *(const float4*)(Bp + k0);
        const float4 b1 = *(const float4*)(Bp + k0 + 4);

        __syncthreads();   // prior chunk's frag reads done
        {
            const float va[8] = {a0.x,a0.y,a0.z,a0.w, a1.x,a1.y,a1.z,a1.w};
            const float vb[8] = {b0.x,b0.y,b0.z,b0.w, b1.x,b1.y,b1.z,b1.w};
            bfrag ha[MODE], hb[MODE];
#pragma unroll
            for (int i = 0; i < 8; ++i) {
                float xa = va[i], xb = vb[i];
#pragma unroll
                for (int s = 0; s < MODE; ++s) {
                    const unsigned short sa = f2bf(xa), sb = f2bf(xb);
                    ha[s][i] = (short)sa; hb[s][i] = (short)sb;
                    xa -= bf2f(sa);       xb -= bf2f(sb);
                }
            }
#pragma unroll
            for (int s = 0; s < MODE; ++s) {
                *(bfrag*)&As[s][sr][sg * 8] = ha[s];
                *(bfrag*)&Bs[s][sr][sg * 8] = hb[s];
            }
        }
        __syncthreads();   // tiles visible

        bfrag af[MODE][2], bf[MODE][2];
#pragma unroll
        for (int t = 0; t < 2; ++t) {
            const int mr = wr * 32 + t * 16 + l15;
            const int nr = wc * 32 + t * 16 + l15;
#pragma unroll
            for (int s = 0; s < MODE; ++s) {
                af[s][t] = *(const bfrag*)&As[s][mr][quad * 8];
                bf[s][t] = *(const bfrag*)&Bs[s][nr][quad * 8];
            }
        }
#pragma unroll
        for (int mt = 0; mt < 2; ++mt)
#pragma unroll
            for (int nt = 0; nt < 2; ++nt) {
                f32x4 c = acc[mt][nt];
                c = __builtin_amdgcn_mfma_f32_16x16x32_bf16(af[0][mt], bf[0][nt], c, 0, 0, 0);
                c = __builtin_amdgcn_mfma_f32_16x16x32_bf16(af[0][mt], bf[1][nt], c, 0, 0, 0);
                c = __builtin_amdgcn_mfma_f32_16x16x32_bf16(af[1][mt], bf[0][nt], c, 0, 0, 0);
                if (MODE == 3) {
                    c = __builtin_amdgcn_mfma_f32_16x16x32_bf16(af[1][mt], bf[1][nt], c, 0, 0, 0);
                    c = __builtin_amdgcn_mfma_f32_16x16x32_bf16(af[0][mt], bf[2][nt], c, 0, 0, 0);
                    c = __builtin_amdgcn_mfma_f32_16x16x32_bf16(af[2][mt], bf[0][nt], c, 0, 0, 0);
                }
                acc[mt][nt] = c;
            }
    }

    // epilogue: C/D frag (col=l15, row=quad*4+g) -> row-major C (+bias)
#pragma unroll
    for (int nt = 0; nt < 2; ++nt) {
        const int col = bn + wc * 32 + nt * 16 + l15;
        const float bv = bias ? bias[col] : 0.f;
#pragma unroll
        for (int mt = 0; mt < 2; ++mt) {
            const int rowb = bm + wr * 32 + mt * 16 + quad * 4;
#pragma unroll
            for (int g = 0; g < 4; ++g)
                C[(size_t)(rowb + g) * N + col] = acc[mt][nt][g] + bv;
        }
    }
}

// ---------------------------------------------------------------------------
// Trellis beam search — bitonic merge (round-2 math, VERIFIED correct) with
// ONE BEAM ELEMENT PER LANE. Round-2's array version spilled to scratch
// (VGPR_Count=72 vs ~150 needed -> 655 us). Here the beam state is 2 VGPRs
// per lane (pen, msk); all merge traffic is shfl_xor:
//   half-cleaner: partner lane^31, L[l] = min(A[l], B[31-l]), tie -> A
//     (matches top_k's stable A-side preference);
//   bitonic merge: k = 16,8,4,2,1; lane keeps min if (l&k)==0 else max;
//     on equal values both lanes keep their OWN pair -> pair multiset
//     preserved (no mask mixups on ties).
// Wave64 = 2 rows (lanes 0-31 / 32-63); xor masks <=31 never cross the
// half. Block = 256 thr = 8 rows, grid = 1024 blocks (vs round-0's 128
// 1-wave blocks on half the CUs). Attribution from round 2: the round-0
// LDS ping-pong trellis was ~110 us (1414.4-868.7 = 545.7 = 655.6 - X);
// serial chain here is ~2.5K cy/row, hidden by occupancy -> ~10 us.
// Numerics: dlt computed with the identical sequential 16-term dot; each
// penalty is the same single add (pen + d); selection multiset identical
// (sentinels 3e38 sort last, beam full after step 5); output order is the
// same ascending-penalty order. Z is butterfly-summed (ulp-level diff vs
// sequential; threshold 4.9e-4).
// ---------------------------------------------------------------------------
#define KPAD 34   // LDS row stride for keys: (l*34+d)%32 = (2l+d)%32 -> 2-way max (free)
__global__ __launch_bounds__(256) void trellis_kernel(
    const float* __restrict__ q, const float* __restrict__ keys,
    float* __restrict__ sc_out, int* __restrict__ idx_out)
{
    __shared__ float s_keys[MEM_HEADS * NUM_BUCKETS * KPAD]; // 2448 floats

    const int tid = threadIdx.x;
    for (int i = tid; i < MEM_HEADS * NUM_BUCKETS * 32; i += 256) {
        const int row = i >> 5, d = i & 31;
        s_keys[row * KPAD + d] = keys[i];
    }
    __syncthreads();

    const int wave = tid >> 6;
    const int lane = tid & 63;
    const int sub  = lane >> 5;          // row-within-wave
    const int l    = lane & 31;          // beam slot / bucket index
    const int r    = blockIdx.x * 8 + wave * 2 + sub;
    const int h    = r & 3;

    // phase 1: lane m (<18) computes bucket m's scores; same sequential
    // accumulation order as the reference kernel -> bit-identical dlt.
    float dlt = 0.f;
    int bit_l = 0;
    if (l < NUM_BUCKETS) {
        const float* km = s_keys + (h * NUM_BUCKETS + l) * KPAD;
        const float* qr = q + (size_t)r * KEY_DIM + l * BUCKET_DIM;
        const float4 q0 = *(const float4*)(qr);
        const float4 q1 = *(const float4*)(qr + 4);
        const float4 q2 = *(const float4*)(qr + 8);
        const float4 q3 = *(const float4*)(qr + 12);
        const float qv[16] = {q0.x,q0.y,q0.z,q0.w, q1.x,q1.y,q1.z,q1.w,
                              q2.x,q2.y,q2.z,q2.w, q3.x,q3.y,q3.z,q3.w};
        float s0 = 0.f, s1 = 0.f;
#pragma unroll
        for (int d = 0; d < BUCKET_DIM; ++d) {
            s0 += qv[d] * km[d];
            s1 += qv[d] * km[16 + d];
        }
        dlt = fabsf(s0 - s1);
        if (s1 > s0) bit_l = 1 << l;
    }
    // OR-butterfly within the 32-lane half -> every lane has the full code
    int code = bit_l;
#pragma unroll
    for (int k = 16; k >= 1; k >>= 1) code |= __shfl_xor(code, k);

    // phase 2: beam, one (pen,msk) per lane, sorted ascending across lanes
    float pen = (l == 0) ? 0.f : 3.0e38f;
    int   msk = 0;
#pragma unroll
    for (int t = 0; t < NUM_BUCKETS; ++t) {
        const float d   = __shfl(dlt, t, 32);     // per-half broadcast
        const int   bit = 1 << t;
        // half-cleaner: A[l] vs B[31-l] = pen[lane^31] + d
        const float pr = __shfl_xor(pen, 31);
        const int   mr = __shfl_xor(msk, 31);
        const float pb = pr + d;
        const bool  ta = (pen <= pb);             // tie -> A side (top_k)
        float p = ta ? pen : pb;
        int   m = ta ? msk : (mr ^ bit);
        // bitonic merge: sorts the bitonic sequence ascending
#pragma unroll
        for (int k = 16; k >= 1; k >>= 1) {
            const float op = __shfl_xor(p, k);
            const int   om = __shfl_xor(m, k);
            const bool  lower = ((l & k) == 0);
            const bool  take  = lower ? (op < p) : (op > p);  // equal: keep own pair
            p = take ? op : p;
            m = take ? om : m;
        }
        pen = p; msk = m;
    }

    // phase 3: softmax (penalty 0 always survives => exp(-pen)/Z) + write
    const float e = expf(-pen);
    float Z = e;
#pragma unroll
    for (int k = 16; k >= 1; k >>= 1) Z += __shfl_xor(Z, k);
    const float inv = 1.0f / Z;
    sc_out[(size_t)r * KNN + l]  = e * inv;
    idx_out[(size_t)r * KNN + l] = code ^ msk;
}

// ---------------------------------------------------------------------------
// Gather + embedding-bag: y[n,:] = sum_k score[n,k] * values[idx[n,k],:]
// One block (128 threads) per token; unroll 8 keeps ~8 float4 loads in
// flight per lane. At its roofline: 512 MB of mandatory random 2KB-row
// reads, L3 flushed by the harness's 2 GiB workspace fill each iteration
// -> ~85-100 us cold-HBM floor. Byte-identical to the 868-us version.
// ---------------------------------------------------------------------------
__global__ __launch_bounds__(128) void gather_kernel(
    const float* __restrict__ sc, const int* __restrict__ idx,
    const float* __restrict__ values, float* __restrict__ y)
{
    __shared__ float s_s[MEM_HEADS * KNN];
    __shared__ int   s_i[MEM_HEADS * KNN];
    const int n = blockIdx.x;
    const int t = threadIdx.x;          // 0..127
    s_s[t] = sc[(size_t)n * 128 + t];
    s_i[t] = idx[(size_t)n * 128 + t];
    __syncthreads();

    float4 acc = {0.f, 0.f, 0.f, 0.f};
#pragma unroll 8
    for (int k = 0; k < 128; ++k) {
        const float4 v = *(const float4*)(values + (size_t)s_i[k] * VALUE_DIM + t * 4);
        const float w = s_s[k];
        acc.x += w * v.x; acc.y += w * v.y;
        acc.z += w * v.z; acc.w += w * v.w;
    }
    *(float4*)(y + (size_t)n * VALUE_DIM + t * 4) = acc;
}

// ---------------------------------------------------------------------------
extern "C" void kernel_launch(void* const* d_in, const int* in_sizes, int n_in,
                              void* d_out, int out_size, void* d_ws, size_t ws_size,
                              hipStream_t stream)
{
    (void)in_sizes; (void)n_in; (void)out_size; (void)ws_size;
    const float* x      = (const float*)d_in[0];
    const float* keys   = (const float*)d_in[1];
    const float* qd_w   = (const float*)d_in[2];
    const float* qd_b   = (const float*)d_in[3];
    const float* qu_w   = (const float*)d_in[4];
    const float* values = (const float*)d_in[5];
    const float* vp_w   = (const float*)d_in[6];
    float* out = (float*)d_out;

    float* q_mid = (float*)d_ws;                       // 2048*512
    float* q     = q_mid + (size_t)NTOK * Q_RANK;      // 2048*1152
    float* sc    = q + (size_t)NTOK * QDIM;            // 8192*32
    int*   idx   = (int*)(sc + (size_t)ROWS * KNN);    // 8192*32
    float* y     = (float*)(idx + (size_t)ROWS * KNN); // 2048*512

    // q_mid = x @ qd_w^T + qd_b    [2048,1024]@[512,1024]^T  (fp32-equiv)
    gemm_nt_split<3><<<dim3(Q_RANK / 64, NTOK / 64), 256, 0, stream>>>(
        x, qd_w, qd_b, q_mid, NTOK, Q_RANK, D_MODEL);
    // q = q_mid @ qu_w^T           [2048,512]@[1152,512]^T   (fp32-equiv)
    gemm_nt_split<3><<<dim3(QDIM / 64, NTOK / 64), 256, 0, stream>>>(
        q_mid, qu_w, nullptr, q, NTOK, QDIM, Q_RANK);
    // beam search -> softmaxed scores + indices (lane-parallel bitonic)
    trellis_kernel<<<ROWS / 8, 256, 0, stream>>>(q, keys, sc, idx);
    // weighted gather -> y [2048, 512]
    gather_kernel<<<NTOK, 128, 0, stream>>>(sc, idx, values, y);
    // out = y @ vp_w^T             [2048,512]@[1024,512]^T   (bf16x3 ok)
    gemm_nt_split<2><<<dim3(D_MODEL / 64, NTOK / 64), 256, 0, stream>>>(
        y, vp_w, nullptr, out, NTOK, D_MODEL, VALUE_DIM);
}